// Round 2
// baseline (211.591 us; speedup 1.0000x reference)
//
#include <hip/hip_runtime.h>
#include <stdint.h>

#define NN 96   // nodes
#define DD 64   // hidden dim
#define NW 3    // 96 bits = 3 u32 words

// ---------- bitmask helpers ----------
__device__ __forceinline__ void below_mask(int K, uint32_t b[NW]) {
#pragma unroll
  for (int w = 0; w < NW; ++w) {
    int s = K - 32 * w;
    b[w] = (s <= 0) ? 0u : ((s >= 32) ? 0xffffffffu : ((1u << s) - 1u));
  }
}

// pa row-mask for node r under pair (U=max(i,j), L=min(i,j)):
//   r < U : adj-neighbors < U, plus U itself if r < L and adj[r][U]
//   r == U: adj-neighbors < L
//   r > U : empty
// plus self-loop bit r.  deg[r] = popcount(mask) (>= 1 always).
__device__ __forceinline__ void row_mask(const uint32_t* A, int r, int U, int L,
                                         uint32_t m[NW]) {
  if (r > U) {
#pragma unroll
    for (int w = 0; w < NW; ++w) m[w] = 0u;
  } else if (r == U) {
    uint32_t b[NW];
    below_mask(L, b);
#pragma unroll
    for (int w = 0; w < NW; ++w) m[w] = A[r * NW + w] & b[w];
  } else {
    uint32_t b[NW];
    below_mask(U, b);
#pragma unroll
    for (int w = 0; w < NW; ++w) m[w] = A[r * NW + w] & b[w];
    if (r < L && ((A[r * NW + (U >> 5)] >> (U & 31)) & 1u))
      m[U >> 5] |= (1u << (U & 31));
  }
  m[r >> 5] |= (1u << (r & 31));
}

// ---------- kernel A: pair-independent precompute ----------
// zw = z @ W1[0:64,:]  (96x64), adjacency bitset (96 x 3 u32)
__global__ void precompute_kernel(const float* __restrict__ z,
                                  const float* __restrict__ adj,
                                  const float* __restrict__ W1,
                                  float* __restrict__ zw,
                                  uint32_t* __restrict__ adjb) {
  int t = threadIdx.x;
  for (int o = t; o < NN * DD; o += 256) {
    int n = o >> 6, k = o & 63;
    float acc = 0.f;
#pragma unroll 8
    for (int m = 0; m < DD; ++m) acc += z[n * DD + m] * W1[m * DD + k];
    zw[o] = acc;
  }
  for (int o = t; o < NN * NW; o += 256) {
    int r = o / NW, w = o % NW;
    uint32_t bits = 0u;
    for (int b = 0; b < 32; ++b) {
      if (adj[r * NN + 32 * w + b] != 0.f) bits |= (1u << b);
    }
    adjb[o] = bits;
  }
}

// ---------- kernel B: one wave per (i,j) pair ----------
__global__ __launch_bounds__(256) void pair_kernel(
    const float* __restrict__ W1, const float* __restrict__ W2,
    const float* __restrict__ zw, const uint32_t* __restrict__ adjbG,
    float* __restrict__ out) {
  __shared__ float zws[NN * DD];       // 24576 B
  __shared__ uint32_t adjb[NN * NW];   // 1152 B
  __shared__ float w64s[DD], w65s[DD], W2s[DD];
  __shared__ float dinv[4][NN];

  int t = threadIdx.x;
  // stage zw (float4), adjacency bits, W1 rows 64/65, W2
  for (int o = t; o < NN * DD / 4; o += 256)
    ((float4*)zws)[o] = ((const float4*)zw)[o];
  for (int o = t; o < NN * NW; o += 256)   // FIX: 288 words > 256 threads
    adjb[o] = adjbG[o];
  if (t < DD) {
    w64s[t] = W1[64 * DD + t];
    w65s[t] = W1[65 * DD + t];
    W2s[t]  = W2[t];
  }
  __syncthreads();

  int wave = t >> 6, lane = t & 63;
  int p = blockIdx.x * 4 + wave;       // pair index, 0..9215
  int i = p / NN, j = p % NN;
  int U = max(i, j), L = min(i, j);

  // deg/dinv for all 96 nodes (lanes cover n and n+64)
  for (int n = lane; n < NN; n += 64) {
    uint32_t m[NW];
    row_mask(adjb, n, U, L, m);
    int deg = __popc(m[0]) + __popc(m[1]) + __popc(m[2]);
    dinv[wave][n] = rsqrtf((float)deg);
  }
  __syncthreads();

  const float* dv = dinv[wave];
  uint32_t mi[NW], mj[NW];
  row_mask(adjb, i, U, L, mi);
  row_mask(adjb, j, U, L, mj);

  float w2k = W2s[lane];
  float w64k = w64s[lane], w65k = w65s[lane];
  float ti = 0.f, tj = 0.f;

  // frontier: c in rowmask(i) | rowmask(j).  All masks are wave-uniform,
  // so the bit-loops do not diverge across lanes.
#pragma unroll
  for (int w = 0; w < NW; ++w) {
    uint32_t mS = mi[w] | mj[w];
    while (mS) {
      int b = __builtin_ctz(mS);
      mS &= mS - 1;
      int c = 32 * w + b;
      uint32_t mc[NW];
      row_mask(adjb, c, U, L, mc);
      float acc = 0.f;
#pragma unroll
      for (int w2 = 0; w2 < NW; ++w2) {
        uint32_t mn = mc[w2];
        while (mn) {
          int b2 = __builtin_ctz(mn);
          mn &= mn - 1;
          int n = 32 * w2 + b2;
          float x = zws[n * DD + lane];
          if (n == i) x += w64k;
          if (n == j) x += w65k;
          acc += dv[n] * x;
        }
      }
      float h = dv[c] * acc;
      h = h > 0.f ? h : 0.f;           // relu
      float prod = h * w2k;            // lane-k partial of s[c]
      float dc = dv[c];
      if ((mi[w] >> b) & 1u) ti += dc * prod;
      if ((mj[w] >> b) & 1u) tj += dc * prod;
    }
  }

  float v = dv[i] * ti + dv[j] * tj;   // lane-partial of t[i]+t[j]
#pragma unroll
  for (int off = 32; off > 0; off >>= 1) v += __shfl_xor(v, off, 64);
  if (lane == 0) out[p] = v;
}

extern "C" void kernel_launch(void* const* d_in, const int* in_sizes, int n_in,
                              void* d_out, int out_size, void* d_ws,
                              size_t ws_size, hipStream_t stream) {
  const float* z   = (const float*)d_in[0];  // 96*64
  const float* adj = (const float*)d_in[1];  // 96*96
  const float* W1  = (const float*)d_in[2];  // 66*64
  const float* W2  = (const float*)d_in[3];  // 64
  float* out = (float*)d_out;                // 9216

  float* zw = (float*)d_ws;                          // 24576 B
  uint32_t* adjb = (uint32_t*)((char*)d_ws + NN * DD * sizeof(float));

  precompute_kernel<<<1, 256, 0, stream>>>(z, adj, W1, zw, adjb);
  pair_kernel<<<(NN * NN) / 4, 256, 0, stream>>>(W1, W2, zw, adjb, out);
}

// Round 3
// 142.285 us; speedup vs baseline: 1.4871x; 1.4871x over previous
//
#include <hip/hip_runtime.h>
#include <stdint.h>

#define NN 96   // nodes
#define DD 64   // hidden dim
#define NW 3    // 96 bits = 3 u32 words
#define WPB 8   // waves per block
#define NPAIR (NN * NN)
#define PERM 1997u  // gcd(1997, 9216) = 1 -> bijection for load balance

// ---------- bitmask helpers ----------
__device__ __forceinline__ void below_mask(int K, uint32_t b[NW]) {
#pragma unroll
  for (int w = 0; w < NW; ++w) {
    int s = K - 32 * w;
    b[w] = (s <= 0) ? 0u : ((s >= 32) ? 0xffffffffu : ((1u << s) - 1u));
  }
}

// pa row-mask for node r under pair (U=max(i,j), L=min(i,j)), incl self-loop.
__device__ __forceinline__ void row_mask(const uint32_t* A, int r, int U, int L,
                                         uint32_t m[NW]) {
  if (r > U) {
#pragma unroll
    for (int w = 0; w < NW; ++w) m[w] = 0u;
  } else if (r == U) {
    uint32_t b[NW];
    below_mask(L, b);
#pragma unroll
    for (int w = 0; w < NW; ++w) m[w] = A[r * NW + w] & b[w];
  } else {
    uint32_t b[NW];
    below_mask(U, b);
#pragma unroll
    for (int w = 0; w < NW; ++w) m[w] = A[r * NW + w] & b[w];
    if (r < L && ((A[r * NW + (U >> 5)] >> (U & 31)) & 1u))
      m[U >> 5] |= (1u << (U & 31));
  }
  m[r >> 5] |= (1u << (r & 31));
}

// ---------- kernel A: pair-independent precompute (96 blocks x 64 thr) ----
// block n: zw[n,:] = z[n,:] @ W1[0:64,:]; adjacency bitset row n via ballot.
__global__ __launch_bounds__(64) void precompute_kernel(
    const float* __restrict__ z, const float* __restrict__ adj,
    const float* __restrict__ W1, float* __restrict__ zw,
    uint32_t* __restrict__ adjb) {
  int n = blockIdx.x, k = threadIdx.x;
  __shared__ float zrow[DD];
  zrow[k] = z[n * DD + k];
  __syncthreads();
  float acc = 0.f;
#pragma unroll 16
  for (int m = 0; m < DD; ++m) acc += zrow[m] * W1[m * DD + k];
  zw[n * DD + k] = acc;

  unsigned long long b0 = __ballot(adj[n * NN + k] != 0.f);  // cols 0..63
  bool hi = (k < 32) ? (adj[n * NN + 64 + k] != 0.f) : false;
  unsigned long long b1 = __ballot(hi);                      // cols 64..95
  if (k == 0) {
    adjb[n * NW + 0] = (uint32_t)b0;
    adjb[n * NW + 1] = (uint32_t)(b0 >> 32);
    adjb[n * NW + 2] = (uint32_t)b1;
  }
}

// ---------- kernel B: one wave per (i,j) pair, 8 waves/block ----------
__global__ __launch_bounds__(512) void pair_kernel(
    const float* __restrict__ W1, const float* __restrict__ W2,
    const float* __restrict__ zw, const uint32_t* __restrict__ adjbG,
    float* __restrict__ out) {
  __shared__ float zws[NN * DD];            // 24576 B
  __shared__ uint32_t adjb[NN * NW];        // 1152 B
  __shared__ float w64s[DD], w65s[DD], W2s[DD];  // 768 B
  __shared__ float dinv[WPB][NN];           // 3072 B
  __shared__ uint32_t rmask[WPB][NN * NW];  // 9216 B   (total ~37.9 KB)

  int t = threadIdx.x;
  for (int o = t; o < NN * DD / 4; o += 512)
    ((float4*)zws)[o] = ((const float4*)zw)[o];
  for (int o = t; o < NN * NW; o += 512) adjb[o] = adjbG[o];
  if (t < DD) {
    w64s[t] = W1[64 * DD + t];
    w65s[t] = W1[65 * DD + t];
    W2s[t]  = W2[t];
  }
  __syncthreads();

  int wave = t >> 6, lane = t & 63;
  int g = blockIdx.x * WPB + wave;          // 0..9215
  int p = (int)(((unsigned)g * PERM) % NPAIR);
  int i = p / NN, j = p % NN;
  int U = max(i, j), L = min(i, j);

  // phase 1: per-wave row masks + dinv for all 96 nodes (cached in LDS)
  uint32_t* rm = rmask[wave];
  for (int n = lane; n < NN; n += 64) {
    uint32_t m[NW];
    row_mask(adjb, n, U, L, m);
    rm[n * NW + 0] = m[0];
    rm[n * NW + 1] = m[1];
    rm[n * NW + 2] = m[2];
    int deg = __popc(m[0]) + __popc(m[1]) + __popc(m[2]);
    dinv[wave][n] = rsqrtf((float)deg);
  }
  __syncthreads();

  const float* dv = dinv[wave];
  float dv_i = dv[i], dv_j = dv[j];
  uint32_t mi[NW], mj[NW];
#pragma unroll
  for (int w = 0; w < NW; ++w) {
    mi[w] = rm[i * NW + w];
    mj[w] = rm[j * NW + w];
  }

  float w2k = W2s[lane];
  float w64k = w64s[lane], w65k = w65s[lane];
  float ti = 0.f, tj = 0.f;

  // frontier: c in rowmask(i) | rowmask(j); all masks wave-uniform.
#pragma unroll
  for (int w = 0; w < NW; ++w) {
    uint32_t mS = mi[w] | mj[w];
    while (mS) {
      int b = __builtin_ctz(mS);
      mS &= mS - 1;
      int c = 32 * w + b;
      uint32_t mc0 = rm[c * NW + 0], mc1 = rm[c * NW + 1], mc2 = rm[c * NW + 2];
      float acc = 0.f;
      uint32_t mn = mc0;
      while (mn) {
        int b2 = __builtin_ctz(mn); mn &= mn - 1;
        int n = b2;
        acc += dv[n] * zws[n * DD + lane];
      }
      mn = mc1;
      while (mn) {
        int b2 = __builtin_ctz(mn); mn &= mn - 1;
        int n = 32 + b2;
        acc += dv[n] * zws[n * DD + lane];
      }
      mn = mc2;
      while (mn) {
        int b2 = __builtin_ctz(mn); mn &= mn - 1;
        int n = 64 + b2;
        acc += dv[n] * zws[n * DD + lane];
      }
      // hoisted one-hot corrections (x[i] += W1[64], x[j] += W1[65])
      uint32_t mcw_i = (i < 32) ? mc0 : (i < 64) ? mc1 : mc2;
      uint32_t mcw_j = (j < 32) ? mc0 : (j < 64) ? mc1 : mc2;
      if ((mcw_i >> (i & 31)) & 1u) acc += dv_i * w64k;
      if ((mcw_j >> (j & 31)) & 1u) acc += dv_j * w65k;

      float dc = dv[c];
      float h = dc * acc;
      h = h > 0.f ? h : 0.f;  // relu
      float prod = h * w2k;
      if ((mi[w] >> b) & 1u) ti += dc * prod;
      if ((mj[w] >> b) & 1u) tj += dc * prod;
    }
  }

  float v = dv_i * ti + dv_j * tj;  // lane-partial of t[i]+t[j]
#pragma unroll
  for (int off = 32; off > 0; off >>= 1) v += __shfl_xor(v, off, 64);
  if (lane == 0) out[p] = v;
}

extern "C" void kernel_launch(void* const* d_in, const int* in_sizes, int n_in,
                              void* d_out, int out_size, void* d_ws,
                              size_t ws_size, hipStream_t stream) {
  const float* z   = (const float*)d_in[0];  // 96*64
  const float* adj = (const float*)d_in[1];  // 96*96
  const float* W1  = (const float*)d_in[2];  // 66*64
  const float* W2  = (const float*)d_in[3];  // 64
  float* out = (float*)d_out;                // 9216

  float* zw = (float*)d_ws;
  uint32_t* adjb = (uint32_t*)((char*)d_ws + NN * DD * sizeof(float));

  precompute_kernel<<<NN, 64, 0, stream>>>(z, adj, W1, zw, adjb);
  pair_kernel<<<NPAIR / WPB, 512, 0, stream>>>(W1, W2, zw, adjb, out);
}